// Round 6
// baseline (146.028 us; speedup 1.0000x reference)
//
#include <hip/hip_runtime.h>
#include <hip/hip_bf16.h>

// ODEFunc: out[i] = x_N(x_i) + sum_j A[i,j] * ( edgeMLP(x_i, x_j) + wA0*x_i + wA1*x_j )
//
// R18 = contiguity attack (DRAM row-thrash diagnosis):
//   R13-R17 scorecard: VALU -20% null, occupancy +15pt null, de-phase null,
//   reg-prefetch null, hand-paced DMA depth-3 = -10%. Invariant: A-supply
//   ~1.5 TB/s (64MB/42us) vs 6.3 TB/s copy ceiling. Little/queueing check:
//   4096 waves x 3KB inflight / 1.5TB/s = 8us loaded latency -> 16 pairs x
//   8/3 us = 43us ✓ exactly the wall; service-limited => depth-independent,
//   explaining all nulls. Difference vs copy bench: copy = contiguous front;
//   ours = 4096 concurrent streams at 16KB stride -> DRAM row-buffer thrash.
//   * Block = 4 CONSECUTIVE rows (64KB contiguous); all 4 waves cooperate on
//     one row at a time (wave w = j-quarter w*1024..+1024); rows sequential.
//     Instantaneous chip footprint: 1024 contiguous ~16-32KB windows instead
//     of 4096 scattered 16KB-strided streams.
//   * Per-wave DMA ring 5 slots x 1KB, depth-4 counted vmcnt(4) (T3/T4);
//     one vmcnt(0) drain before the last 4 (LDS-resident) pairs.
//   * bias restored as MFMA C-operand (cbias): -4 VALU/group, f32 bias-add
//     before relu (R12 numerics, absmax was 9.8e-4).
//   * LDS: xs 16KB + ring 4x5KB + partial = 36.9KB -> 4 blocks/CU exact.
//
// MFMA layout (32x32x16, validated R2-R11):
//   A[m][k]: m = lane&31, k = (lane>>5)*8 + e
//   B[k][n]: n = lane&31, k = (lane>>5)*8 + e
//   D[m][n]: n = lane&31, m = (reg&3) + 8*(reg>>2) + 4*(lane>>5)
// Only m<16 carries WA1; D regs 8..15 ignored. C = cbias (bA1 in D regs 0..7).
// In-lane epilogue: A_ij distributes into the WA2 dot; skip term in half 0 only.

#define NN 4096

typedef __fp16 half8  __attribute__((ext_vector_type(8)));
typedef __fp16 half2v __attribute__((ext_vector_type(2)));
typedef __attribute__((ext_vector_type(4)))  float f32x4;
typedef __attribute__((ext_vector_type(16))) float f32x16;

__device__ __forceinline__ half2v cvt2(float lo, float hi) {
    return __builtin_amdgcn_cvt_pkrtz(lo, hi);
}

__global__ __launch_bounds__(256, 4) void odef_kernel(
    const float* __restrict__ x,  const float* __restrict__ A,
    const float* __restrict__ WA0, const float* __restrict__ bA0,
    const float* __restrict__ WA1, const float* __restrict__ bA1,
    const float* __restrict__ WA2, const float* __restrict__ bA2,
    const float* __restrict__ Wm0, const float* __restrict__ bm0,
    const float* __restrict__ Wm1, const float* __restrict__ bm1,
    const float* __restrict__ wA,  const float* __restrict__ wf,
    float* __restrict__ out)
{
    __shared__ float xs[NN];              // full x vector, 16KB
    __shared__ float ring[4][5][256];     // [wave][slot][1KB] DMA ring, 20KB
    __shared__ float partial[4][4];       // [row][wave]

    const int tid  = threadIdx.x;
    const int wave = tid >> 6;
    const int lane = tid & 63;
    const int n    = lane & 31;      // MFMA col (B n / D n / A m)
    const int half = lane >> 5;      // k-half (A/B), row-half (D)
    const int r0   = blockIdx.x * 4; // 4 consecutive rows per block

    // ---- cooperative x -> LDS (1024 float4, 4 per thread)
    {
        const f32x4* xsrc = (const f32x4*)x;
        f32x4* xdst = (f32x4*)xs;
        #pragma unroll
        for (int i = 0; i < 4; ++i)
            xdst[tid + 256 * i] = xsrc[tid + 256 * i];
    }
    const float xq0 = x[r0], xq1 = x[r0 + 1], xq2 = x[r0 + 2], xq3 = x[r0 + 3];

    __syncthreads();   // xs visible; drains all vmem -> clean vmcnt baseline

    // DMA pair g (0..15): row = r0 + (g>>2), this wave's quarter, chunk g&3.
    // LDS dest: wave-uniform base, HW writes base + lane*16 (linear 1KB).
    const float* abase = A + (size_t)r0 * NN + wave * 1024 + lane * 4;
    auto issue = [&](int g, int slot) {
        const float* src = abase + (g >> 2) * NN + (g & 3) * 256;
        __builtin_amdgcn_global_load_lds(
            (const __attribute__((address_space(1))) void*)src,
            (__attribute__((address_space(3))) void*)&ring[wave][slot][0],
            16, 0, 0);
    };
    issue(0, 0); issue(1, 1); issue(2, 2); issue(3, 3);   // prologue, depth 4

    // ---- A-fragment: WA1[m][k] in f16; m = n (<16), k = half*8 + e
    union { half2v h2[4]; half8 h8; } au;
    #pragma unroll
    for (int p = 0; p < 4; ++p) {
        float lo = 0.f, hi = 0.f;
        if (n < 16) {
            int k = half * 8 + p * 2;
            lo = WA1[n * 16 + k];
            hi = WA1[n * 16 + k + 1];
        }
        au.h2[p] = cvt2(lo, hi);
    }

    // ---- h0 constants for all 4 rows: u_k(i) = WA0[k,0]*xi + bA0[k]; w1_k
    half2v w2h[4], uA[4], uB[4], uC[4], uD[4];
    #pragma unroll
    for (int p = 0; p < 4; ++p) {
        int k0 = half * 8 + p * 2;
        float alo = WA0[2 * k0],     ahi = WA0[2 * k0 + 2];
        float blo = bA0[k0],         bhi = bA0[k0 + 1];
        w2h[p] = cvt2(WA0[2 * k0 + 1], WA0[2 * k0 + 3]);
        uA[p] = cvt2(fmaf(alo, xq0, blo), fmaf(ahi, xq0, bhi));
        uB[p] = cvt2(fmaf(alo, xq1, blo), fmaf(ahi, xq1, bhi));
        uC[p] = cvt2(fmaf(alo, xq2, blo), fmaf(ahi, xq2, bhi));
        uD[p] = cvt2(fmaf(alo, xq3, blo), fmaf(ahi, xq3, bhi));
    }

    // ---- layer-2 weights + bias-as-C (rows (r&3)+8*(r>>2)+4*half, r<8)
    half2v wa2h[4];
    f32x16 cbias;
    #pragma unroll
    for (int r = 0; r < 16; ++r) cbias[r] = 0.f;
    #pragma unroll
    for (int r = 0; r < 8; ++r) {
        int m = (r & 3) + 8 * (r >> 2) + 4 * half;
        cbias[r] = bA1[m];
    }
    #pragma unroll
    for (int p = 0; p < 4; ++p) {
        int m0 = (2 * p & 3) + 8 * (2 * p >> 2) + 4 * half;
        wa2h[p] = cvt2(WA2[m0], WA2[m0 + 1]);
    }

    // skip term: only half 0 adds it (each j held by exactly one lane-pair)
    const float wA1h = half ? 0.f : wA[1];
    const float c0A = half ? 0.f : (bA2[0] + wA[0] * xq0);
    const float c0B = half ? 0.f : (bA2[0] + wA[0] * xq1);
    const float c0C = half ? 0.f : (bA2[0] + wA[0] * xq2);
    const float c0D = half ? 0.f : (bA2[0] + wA[0] * xq3);
    const half2v z2 = { (__fp16)0.f, (__fp16)0.f };

    float acc0 = 0.f, acc1 = 0.f;
    half2v u2h[4];
    float c0h = 0.f;

    // one 128-j group: 4 MFMA sub-groups, 2-deep MFMA pipeline (proven R10+)
    auto body = [&](const f32x4 xv, const f32x4 av) {
        #pragma unroll
        for (int q = 0; q < 4; q += 2) {
            half2v xg0 = cvt2(xv[q], xv[q]);
            union { half2v h2[4]; half8 h8; } b0;
            #pragma unroll
            for (int p = 0; p < 4; ++p)
                b0.h2[p] = __builtin_elementwise_max(w2h[p] * xg0 + u2h[p], z2);
            f32x16 d0 = __builtin_amdgcn_mfma_f32_32x32x16_f16(au.h8, b0.h8, cbias, 0, 0, 0);

            half2v xg1 = cvt2(xv[q + 1], xv[q + 1]);
            union { half2v h2[4]; half8 h8; } b1;
            #pragma unroll
            for (int p = 0; p < 4; ++p)
                b1.h2[p] = __builtin_elementwise_max(w2h[p] * xg1 + u2h[p], z2);
            f32x16 d1 = __builtin_amdgcn_mfma_f32_32x32x16_f16(au.h8, b1.h8, cbias, 0, 0, 0);

            // epilogue q: relu in f32 via max after cvt (bias already in d)
            {
                float pp = fmaf(wA1h, xv[q], c0h);
                #pragma unroll
                for (int p = 0; p < 4; ++p) {
                    half2v t = __builtin_elementwise_max(cvt2(d0[2 * p], d0[2 * p + 1]), z2);
                    pp = __builtin_amdgcn_fdot2(t, wa2h[p], pp, false);
                }
                acc0 = fmaf(av[q], pp, acc0);
            }
            // epilogue q+1
            {
                float pp = fmaf(wA1h, xv[q + 1], c0h);
                #pragma unroll
                for (int p = 0; p < 4; ++p) {
                    half2v t = __builtin_elementwise_max(cvt2(d1[2 * p], d1[2 * p + 1]), z2);
                    pp = __builtin_amdgcn_fdot2(t, wa2h[p], pp, false);
                }
                acc1 = fmaf(av[q + 1], pp, acc1);
            }
        }
    };

    int sl_c = 0;   // consume slot = g % 5
    int sl_i = 4;   // issue slot  = (g+4) % 5

    auto consume = [&](int g) {
        const int p4 = g & 3;
        if (p4 == 0) {               // new row: select row constants
            const int rr = g >> 2;
            #pragma unroll
            for (int p = 0; p < 4; ++p)
                u2h[p] = rr == 0 ? uA[p] : rr == 1 ? uB[p] : rr == 2 ? uC[p] : uD[p];
            c0h = rr == 0 ? c0A : rr == 1 ? c0B : rr == 2 ? c0C : c0D;
        }
        const f32x4* sp = (const f32x4*)&ring[wave][sl_c][0];
        sl_c = (sl_c == 4) ? 0 : sl_c + 1;
        const f32x4* xq = (const f32x4*)(xs + wave * 1024 + p4 * 256);
        f32x4 av0 = sp[n],      xv0 = xq[n];
        f32x4 av1 = sp[32 + n], xv1 = xq[32 + n];
        body(xv0, av0);
        body(xv1, av1);
        if (p4 == 3) {               // row done: reduce + stash, reset acc
            float a = acc0 + acc1;
            #pragma unroll
            for (int off = 32; off > 0; off >>= 1)
                a += __shfl_xor(a, off);
            if (lane == 0) partial[g >> 2][wave] = a;
            acc0 = 0.f; acc1 = 0.f;
        }
    };

    // main: 12 paced pairs; issue g+4, counted vmcnt(4) keeps 4KB/wave in flight
    for (int g = 0; g < 12; ++g) {
        issue(g + 4, sl_i);
        sl_i = (sl_i == 4) ? 0 : sl_i + 1;
        asm volatile("s_waitcnt vmcnt(4)" ::: "memory");
        __builtin_amdgcn_sched_barrier(0);
        consume(g);
    }
    // tail: everything already issued; one drain, then 4 LDS-resident pairs
    asm volatile("s_waitcnt vmcnt(0)" ::: "memory");
    __builtin_amdgcn_sched_barrier(0);
    for (int g = 12; g < 16; ++g)
        consume(g);

    __syncthreads();

    // ---- per-row combine + node MLP (fp32 exact), threads 0..3 = rows 0..3
    if (tid < 4) {
        const float xi = x[r0 + tid];
        float s = partial[tid][0] + partial[tid][1] + partial[tid][2] + partial[tid][3];
        float xn = fmaf(wf[0], xi, bm1[0]);
        #pragma unroll
        for (int h = 0; h < 16; ++h)
            xn = fmaf(Wm1[h], fmaxf(fmaf(Wm0[h], xi, bm0[h]), 0.f), xn);
        out[r0 + tid] = xn + s;
    }
}

extern "C" void kernel_launch(void* const* d_in, const int* in_sizes, int n_in,
                              void* d_out, int out_size, void* d_ws, size_t ws_size,
                              hipStream_t stream) {
    const float* x   = (const float*)d_in[1];
    const float* A   = (const float*)d_in[2];
    const float* WA0 = (const float*)d_in[3];
    const float* bA0 = (const float*)d_in[4];
    const float* WA1 = (const float*)d_in[5];
    const float* bA1 = (const float*)d_in[6];
    const float* WA2 = (const float*)d_in[7];
    const float* bA2 = (const float*)d_in[8];
    const float* Wm0 = (const float*)d_in[9];
    const float* bm0 = (const float*)d_in[10];
    const float* Wm1 = (const float*)d_in[11];
    const float* bm1 = (const float*)d_in[12];
    const float* wA  = (const float*)d_in[13];
    const float* wf  = (const float*)d_in[14];
    float* out = (float*)d_out;

    odef_kernel<<<NN / 4, 256, 0, stream>>>(x, A, WA0, bA0, WA1, bA1, WA2, bA2,
                                            Wm0, bm0, Wm1, bm1, wA, wf, out);
}

// Round 8
// 145.284 us; speedup vs baseline: 1.0051x; 1.0051x over previous
//
#include <hip/hip_runtime.h>
#include <hip/hip_bf16.h>

// ODEFunc: out[i] = x_N(x_i) + sum_j A[i,j] * ( edgeMLP(x_i, x_j) + wA0*x_i + wA1*x_j )
//
// R20 = R19 (per-lane asm-paced register pipeline, depth 8) with the
// register-hazard fixed:
//   R19 FAILED (absmax 105): slot regs a0..a7 were loop-carried asm outputs;
//   the compiler's phi-copies at the back edge (v_mov) read the asm loads'
//   destination registers while the data was still in flight -> garbage.
//   The compiler cannot know an asm global_load writes asynchronously; ANY
//   copy/spill between issue and the retiring s_waitcnt is poison.
//   * Fix: straight-line SSA. All 32 steps fully unrolled; 32 single-
//     assignment f32x4 slots L0..L31, each written by exactly one asm load,
//     read by exactly one body, <=8 live at once -> no phis, no copies.
//   * Pipeline semantics identical to R19 (verified by construction):
//     - explicit vmcnt(0) baseline drain -> our loads are the ONLY vmem ops
//       counted in the loop (x via LDS, constants in regs, store at end);
//     - prologue issues L0..L7; step t: WAITV(7) retires oldest (=Lt),
//       body consumes Lt, then issues L(t+8); tail steps 24..31 use
//       descending vmcnt(7..0) with no new issues;
//     - volatile-asm program order + sched_barrier(0) after every wait
//       (rule #18) pins the schedule.
//   Steady state: 8KB/wave in flight, 16 waves/CU -> service-saturating
//   demand; each load ages ~8 body-lengths before its wait.
//   Mapping: R17's (1 wave = 1 full row, 4 rows/block, grid 1024 = 4
//   blocks/CU, no tail). Body/numerics verbatim R17 (passed, absmax 7.8e-3).
//
// MFMA layout (32x32x16, validated R2-R11):
//   A[m][k]: m = lane&31, k = (lane>>5)*8 + e
//   B[k][n]: n = lane&31, k = (lane>>5)*8 + e
//   D[m][n]: n = lane&31, m = (reg&3) + 8*(reg>>2) + 4*(lane>>5)
// Only m<16 carries WA1; D regs 8..15 ignored. C = 0 (bA1 applied in epilogue).
// In-lane epilogue: A_ij distributes into the WA2 dot; skip term in half 0 only.

#define NN 4096

typedef __fp16 half8  __attribute__((ext_vector_type(8)));
typedef __fp16 half2v __attribute__((ext_vector_type(2)));
typedef __attribute__((ext_vector_type(4)))  float f32x4;
typedef __attribute__((ext_vector_type(16))) float f32x16;

__device__ __forceinline__ half2v cvt2(float lo, float hi) {
    return __builtin_amdgcn_cvt_pkrtz(lo, hi);
}

__global__ __launch_bounds__(256, 4) void odef_kernel(
    const float* __restrict__ x,  const float* __restrict__ A,
    const float* __restrict__ WA0, const float* __restrict__ bA0,
    const float* __restrict__ WA1, const float* __restrict__ bA1,
    const float* __restrict__ WA2, const float* __restrict__ bA2,
    const float* __restrict__ Wm0, const float* __restrict__ bm0,
    const float* __restrict__ Wm1, const float* __restrict__ bm1,
    const float* __restrict__ wA,  const float* __restrict__ wf,
    float* __restrict__ out)
{
    __shared__ float xs[NN];         // full x vector, 16KB

    const int tid  = threadIdx.x;
    const int wave = tid >> 6;
    const int lane = tid & 63;
    const int n    = lane & 31;      // MFMA col (B n / D n / A m)
    const int half = lane >> 5;      // k-half (A/B), row-half (D)
    const int row  = blockIdx.x * 4 + wave;   // 1 full row per wave

    // ---- cooperative x -> LDS (1024 float4, 4 per thread)
    {
        const f32x4* xsrc = (const f32x4*)x;
        f32x4* xdst = (f32x4*)xs;
        #pragma unroll
        for (int i = 0; i < 4; ++i)
            xdst[tid + 256 * i] = xsrc[tid + 256 * i];
    }
    const float xi = x[row];

    // ---- A-fragment: WA1[m][k] in f16; m = n (<16), k = half*8 + e
    union { half2v h2[4]; half8 h8; } au;
    #pragma unroll
    for (int p = 0; p < 4; ++p) {
        float lo = 0.f, hi = 0.f;
        if (n < 16) {
            int k = half * 8 + p * 2;
            lo = WA1[n * 16 + k];
            hi = WA1[n * 16 + k + 1];
        }
        au.h2[p] = cvt2(lo, hi);
    }

    // ---- h0 constants, packed f16: u_k(i) = WA0[k,0]*xi + bA0[k]; w1_k = WA0[k,1]
    half2v u2h[4], w2h[4];
    #pragma unroll
    for (int p = 0; p < 4; ++p) {
        int k0 = half * 8 + p * 2;
        u2h[p] = cvt2(fmaf(WA0[2 * k0],     xi, bA0[k0]),
                      fmaf(WA0[2 * k0 + 2], xi, bA0[k0 + 1]));
        w2h[p] = cvt2(WA0[2 * k0 + 1], WA0[2 * k0 + 3]);
    }

    // ---- layer-2 weights + bA1 as packed-f16 pairs matching D regs (2p, 2p+1)
    half2v wa2h[4], bb[4];
    #pragma unroll
    for (int p = 0; p < 4; ++p) {
        int r  = 2 * p;
        int m0 = (r & 3) + 8 * (r >> 2) + 4 * half;
        wa2h[p] = cvt2(WA2[m0], WA2[m0 + 1]);
        bb[p]   = cvt2(bA1[m0], bA1[m0 + 1]);
    }

    // skip term: only half 0 adds it (each j is held by both halves)
    const float wA1h = half ? 0.f : wA[1];
    const float c0h  = half ? 0.f : (bA2[0] + wA[0] * xi);
    const half2v z2 = { (__fp16)0.f, (__fp16)0.f };
    const f32x16 zc = {};   // zero C-operand -> folds to MFMA inline constant 0

    float acc0 = 0.f, acc1 = 0.f;

    // one 128-j group: 4 MFMA sub-groups, 2-deep MFMA pipeline (proven R10+)
    auto body = [&](const f32x4 xv, const f32x4 av) {
        #pragma unroll
        for (int q = 0; q < 4; q += 2) {
            half2v xg0 = cvt2(xv[q], xv[q]);
            union { half2v h2[4]; half8 h8; } b0;
            #pragma unroll
            for (int p = 0; p < 4; ++p)
                b0.h2[p] = __builtin_elementwise_max(w2h[p] * xg0 + u2h[p], z2);
            f32x16 d0 = __builtin_amdgcn_mfma_f32_32x32x16_f16(au.h8, b0.h8, zc, 0, 0, 0);

            half2v xg1 = cvt2(xv[q + 1], xv[q + 1]);
            union { half2v h2[4]; half8 h8; } b1;
            #pragma unroll
            for (int p = 0; p < 4; ++p)
                b1.h2[p] = __builtin_elementwise_max(w2h[p] * xg1 + u2h[p], z2);
            f32x16 d1 = __builtin_amdgcn_mfma_f32_32x32x16_f16(au.h8, b1.h8, zc, 0, 0, 0);

            // epilogue q: packed-f16, D regs 0..7 (rows < 16)
            {
                float pp = fmaf(wA1h, xv[q], c0h);
                #pragma unroll
                for (int p = 0; p < 4; ++p) {
                    half2v t = __builtin_elementwise_max(
                        cvt2(d0[2 * p], d0[2 * p + 1]) + bb[p], z2);
                    pp = __builtin_amdgcn_fdot2(t, wa2h[p], pp, false);
                }
                acc0 = fmaf(av[q], pp, acc0);
            }
            // epilogue q+1
            {
                float pp = fmaf(wA1h, xv[q + 1], c0h);
                #pragma unroll
                for (int p = 0; p < 4; ++p) {
                    half2v t = __builtin_elementwise_max(
                        cvt2(d1[2 * p], d1[2 * p + 1]) + bb[p], z2);
                    pp = __builtin_amdgcn_fdot2(t, wa2h[p], pp, false);
                }
                acc1 = fmaf(av[q + 1], pp, acc1);
            }
        }
    };

    __syncthreads();                 // xs ready

    // step t (0..31): lane covers float4 index n + 32t -> floats 4n + 128t.
    const float* ap = A + (size_t)row * NN + 4 * n;
    const f32x4* xls = (const f32x4*)xs;

    // asm load: invisible to compiler's waitcnt pass; paced ONLY by our waits.
#define LOADA(dst, p) \
    asm volatile("global_load_dwordx4 %0, %1, off" : "=v"(dst) : "v"(p))
#define WAITV(N) do {                                              \
    asm volatile("s_waitcnt vmcnt(" #N ")" ::: "memory");          \
    __builtin_amdgcn_sched_barrier(0); } while (0)

    // baseline: drain ALL prior vmem (constant-setup loads) -> counter exact
    __builtin_amdgcn_sched_barrier(0);
    asm volatile("s_waitcnt vmcnt(0)" ::: "memory");
    __builtin_amdgcn_sched_barrier(0);

    // 32 single-assignment slots: each written by ONE asm load, read by ONE
    // body, <=8 live at any point -> no phis, no compiler copies (R19's bug).
    f32x4 L0,  L1,  L2,  L3,  L4,  L5,  L6,  L7,
          L8,  L9,  L10, L11, L12, L13, L14, L15,
          L16, L17, L18, L19, L20, L21, L22, L23,
          L24, L25, L26, L27, L28, L29, L30, L31;

    LOADA(L0, ap + 128 * 0);  LOADA(L1, ap + 128 * 1);
    LOADA(L2, ap + 128 * 2);  LOADA(L3, ap + 128 * 3);
    LOADA(L4, ap + 128 * 4);  LOADA(L5, ap + 128 * 5);
    LOADA(L6, ap + 128 * 6);  LOADA(L7, ap + 128 * 7);

    // steps 0..23: wait-for-oldest = vmcnt(7), consume Lt, issue L(t+8)
#define STEPM(T, CUR, NXT) {                                       \
        f32x4 xv = xls[n + 32 * (T)];                              \
        WAITV(7);                                                  \
        body(xv, CUR);                                             \
        LOADA(NXT, ap + 128 * ((T) + 8)); }

    STEPM(0,  L0,  L8)   STEPM(1,  L1,  L9)   STEPM(2,  L2,  L10)
    STEPM(3,  L3,  L11)  STEPM(4,  L4,  L12)  STEPM(5,  L5,  L13)
    STEPM(6,  L6,  L14)  STEPM(7,  L7,  L15)  STEPM(8,  L8,  L16)
    STEPM(9,  L9,  L17)  STEPM(10, L10, L18)  STEPM(11, L11, L19)
    STEPM(12, L12, L20)  STEPM(13, L13, L21)  STEPM(14, L14, L22)
    STEPM(15, L15, L23)  STEPM(16, L16, L24)  STEPM(17, L17, L25)
    STEPM(18, L18, L26)  STEPM(19, L19, L27)  STEPM(20, L20, L28)
    STEPM(21, L21, L29)  STEPM(22, L22, L30)  STEPM(23, L23, L31)

    // tail: steps 24..31, descending counts, no new issues
#define STEPT(T, WN, CUR) {                                        \
        f32x4 xv = xls[n + 32 * (T)];                              \
        WAITV(WN);                                                 \
        body(xv, CUR); }

    STEPT(24, 7, L24) STEPT(25, 6, L25) STEPT(26, 5, L26) STEPT(27, 4, L27)
    STEPT(28, 3, L28) STEPT(29, 2, L29) STEPT(30, 1, L30) STEPT(31, 0, L31)

#undef STEPM
#undef STEPT
#undef LOADA
#undef WAITV

    // ---- full-wave reduce; each wave owns its row
    float acc = acc0 + acc1;
    #pragma unroll
    for (int off = 32; off > 0; off >>= 1)
        acc += __shfl_xor(acc, off);

    if (lane == 0) {
        // node MLP (fp32 exact): x_N = relu(x*Wm0+bm0)@Wm1 + bm1 + wf*x
        float xn = fmaf(wf[0], xi, bm1[0]);
        #pragma unroll
        for (int h = 0; h < 16; ++h)
            xn = fmaf(Wm1[h], fmaxf(fmaf(Wm0[h], xi, bm0[h]), 0.f), xn);
        out[row] = xn + acc;
    }
}

extern "C" void kernel_launch(void* const* d_in, const int* in_sizes, int n_in,
                              void* d_out, int out_size, void* d_ws, size_t ws_size,
                              hipStream_t stream) {
    const float* x   = (const float*)d_in[1];
    const float* A   = (const float*)d_in[2];
    const float* WA0 = (const float*)d_in[3];
    const float* bA0 = (const float*)d_in[4];
    const float* WA1 = (const float*)d_in[5];
    const float* bA1 = (const float*)d_in[6];
    const float* WA2 = (const float*)d_in[7];
    const float* bA2 = (const float*)d_in[8];
    const float* Wm0 = (const float*)d_in[9];
    const float* bm0 = (const float*)d_in[10];
    const float* Wm1 = (const float*)d_in[11];
    const float* bm1 = (const float*)d_in[12];
    const float* wA  = (const float*)d_in[13];
    const float* wf  = (const float*)d_in[14];
    float* out = (float*)d_out;

    odef_kernel<<<NN / 4, 256, 0, stream>>>(x, A, WA0, bA0, WA1, bA1, WA2, bA2,
                                            Wm0, bm0, Wm1, bm1, wA, wf, out);
}